// Round 6
// baseline (276.874 us; speedup 1.0000x reference)
//
#include <hip/hip_runtime.h>
#include <hip/hip_bf16.h>

// Sorted segment-sum, segment-ownership (no atomics, no memset).
// float4 lane layout: lane = 16*q + r; quarter q owns fragment f+4g+q of each
// 4-fragment group g, r owns dims [4r,4r+4) as float4. One dwordx4 load per
// lane covers 4 fragments (1KB/wave-instr). Segment flush = cross-quarter
// butterfly (shfl_xor 16,32) + one dwordx4 NT store from lanes<16.
// 2-deep A/B software pipeline; NT policy on zero-reuse streams.

#define SEGS_PER_WAVE 64
#define D_EMBED 64
#define BATCH 16

typedef float f32x4 __attribute__((ext_vector_type(4)));

__device__ inline int lower_bound(const int* __restrict__ idx, int n, int v) {
    int lo = 0, hi = n;
    while (lo < hi) {
        int mid = (lo + hi) >> 1;
        if (idx[mid] < v) lo = mid + 1; else hi = mid;
    }
    return lo;
}

__global__ __launch_bounds__(256) void seg_sum_kernel(
        const float* __restrict__ emb,
        const int*   __restrict__ idx,
        float*       __restrict__ out,
        int n_frag, int n_seg) {
    const int gtid = blockIdx.x * blockDim.x + threadIdx.x;
    const int wave = gtid >> 6;
    const int lane = threadIdx.x & 63;
    const int q    = lane >> 4;    // quarter: which fragment of a 4-group
    const int r    = lane & 15;    // float4 slot within a fragment

    const int s0 = wave * SEGS_PER_WAVE;
    if (s0 >= n_seg) return;
    const int s1 = min(s0 + SEGS_PER_WAVE, n_seg);

    int       f  = lower_bound(idx, n_frag, s0);
    const int f1 = lower_bound(idx, n_frag, s1);

    const f32x4 ZERO4 = {0.f, 0.f, 0.f, 0.f};
    int   cur = -1;      // segment currently accumulating (-1 = none yet)
    int   nxt = s0;      // next segment id still needing its output written
    f32x4 acc = ZERO4;

    // flush cur (if any) + zero-fill empties, then start segment s
    auto BOUNDARY = [&](int s) {
        if (cur >= 0) {
            f32x4 t = acc;
            t[0] += __shfl_xor(t[0], 16); t[1] += __shfl_xor(t[1], 16);
            t[2] += __shfl_xor(t[2], 16); t[3] += __shfl_xor(t[3], 16);
            t[0] += __shfl_xor(t[0], 32); t[1] += __shfl_xor(t[1], 32);
            t[2] += __shfl_xor(t[2], 32); t[3] += __shfl_xor(t[3], 32);
            if (lane < 16)
                __builtin_nontemporal_store(t, (f32x4*)(out + (long)cur * D_EMBED) + r);
            nxt = cur + 1;
        }
        for (int z = nxt; z < s; ++z)            // empty segments -> zeros
            if (lane < 16)
                __builtin_nontemporal_store(ZERO4, (f32x4*)(out + (long)z * D_EMBED) + r);
        cur = s; nxt = s; acc = ZERO4;
    };

    f32x4 a0, a1, a2, a3, b0, b1, b2, b3;
    int   mA = 0, mB = 0;

    auto LOAD_A = [&](long fb) {
        mA = idx[fb + r];                        // one 64B line, broadcast
        const f32x4* bp = (const f32x4*)(emb + fb * D_EMBED) + lane;
        a0 = __builtin_nontemporal_load(bp);
        a1 = __builtin_nontemporal_load(bp + 64);
        a2 = __builtin_nontemporal_load(bp + 128);
        a3 = __builtin_nontemporal_load(bp + 192);
    };
    auto LOAD_B = [&](long fb) {
        mB = idx[fb + r];
        const f32x4* bp = (const f32x4*)(emb + fb * D_EMBED) + lane;
        b0 = __builtin_nontemporal_load(bp);
        b1 = __builtin_nontemporal_load(bp + 64);
        b2 = __builtin_nontemporal_load(bp + 128);
        b3 = __builtin_nontemporal_load(bp + 192);
    };
    auto WALK = [&](const f32x4& v0, const f32x4& v1, const f32x4& v2,
                    const f32x4& v3, int mseg) {
#pragma unroll
        for (int j = 0; j < BATCH; ++j) {
            int s = __builtin_amdgcn_readlane(mseg, j);
            if (s != cur) BOUNDARY(s);           // wave-uniform, ~1-in-4
            const f32x4 vj = (j >> 2) == 0 ? v0 : (j >> 2) == 1 ? v1
                           : (j >> 2) == 2 ? v2 : v3;   // static after unroll
            if (q == (j & 3)) acc += vj;         // exec-masked adds
        }
    };

    const int nfull = (f1 - f) >> 4;             // full 16-frag batches
    long fcur = f;
    int  b = 0;
    if (nfull > 0) LOAD_A(fcur);
    while (b < nfull) {
        if (b + 1 < nfull) LOAD_B(fcur + BATCH); // prefetch before walk
        WALK(a0, a1, a2, a3, mA);
        fcur += BATCH; ++b;
        if (b >= nfull) break;
        if (b + 1 < nfull) LOAD_A(fcur + BATCH);
        WALK(b0, b1, b2, b3, mB);
        fcur += BATCH; ++b;
    }

    // tail: < 16 fragments, one at a time (quarter 0 accumulates)
    for (long ff = (long)f + (long)nfull * BATCH; ff < f1; ++ff) {
        int s = idx[ff];                         // uniform
        f32x4 v = __builtin_nontemporal_load(
            (const f32x4*)(emb + ff * D_EMBED) + r);   // quarters replicate
        if (s != cur) BOUNDARY(s);
        if (q == 0) acc += v;
    }

    // final flush + trailing empty segments
    BOUNDARY(s1);
}

extern "C" void kernel_launch(void* const* d_in, const int* in_sizes, int n_in,
                              void* d_out, int out_size, void* d_ws, size_t ws_size,
                              hipStream_t stream) {
    const float* emb = (const float*)d_in[0];
    const int*   idx = (const int*)d_in[1];
    float*       out = (float*)d_out;

    const int n_frag = in_sizes[0] / D_EMBED;   // 4,000,000
    const int n_seg  = out_size / D_EMBED;      // 1,000,000

    const int n_waves  = (n_seg + SEGS_PER_WAVE - 1) / SEGS_PER_WAVE;
    const int block    = 256;                   // 4 waves / block
    const int waves_pb = block / 64;
    const int grid     = (n_waves + waves_pb - 1) / waves_pb;

    seg_sum_kernel<<<grid, block, 0, stream>>>(emb, idx, out, n_frag, n_seg);
}

// Round 7
// 254.778 us; speedup vs baseline: 1.0867x; 1.0867x over previous
//
#include <hip/hip_runtime.h>
#include <hip/hip_bf16.h>

// Sorted segment-sum, segment-ownership (no atomics, no memset).
// R5 walk (lane = dim, readlane-driven boundaries, dword NT stores) +
// WIDE staging: global [frag][dim] layout == desired LDS layout, so each
// 16-frag batch is a linear 4KB copy: 4 x (f32x4 NT load -> ds_write_b128)
// into a wave-private LDS slot; walk reads lds[j*64+lane] (2-way alias, free).
// Pipeline: issue batch k+1's global loads before walking batch k; ds_write
// after the walk absorbs the load latency. All waits compiler-managed.

#define SEGS_PER_WAVE 64
#define D_EMBED 64
#define BATCH 16

typedef float f32x4 __attribute__((ext_vector_type(4)));

__device__ inline int lower_bound(const int* __restrict__ idx, int n, int v) {
    int lo = 0, hi = n;
    while (lo < hi) {
        int mid = (lo + hi) >> 1;
        if (idx[mid] < v) lo = mid + 1; else hi = mid;
    }
    return lo;
}

__global__ __launch_bounds__(256) void seg_sum_kernel(
        const float* __restrict__ emb,
        const int*   __restrict__ idx,
        float*       __restrict__ out,
        int n_frag, int n_seg) {
    __shared__ float lds[4][BATCH * D_EMBED];   // 4 waves x 4KB slots

    const int gtid = blockIdx.x * blockDim.x + threadIdx.x;
    const int wave = gtid >> 6;
    const int lane = threadIdx.x & 63;
    float* lw = lds[(threadIdx.x >> 6) & 3];    // this wave's slot

    const int s0 = wave * SEGS_PER_WAVE;
    if (s0 >= n_seg) return;
    const int s1 = min(s0 + SEGS_PER_WAVE, n_seg);

    int       f  = lower_bound(idx, n_frag, s0);
    const int f1 = lower_bound(idx, n_frag, s1);

    int   cur = -1;    // segment currently accumulating (-1 = none yet)
    int   nxt = s0;    // next segment id still needing its output written
    float acc = 0.0f;

    auto BOUNDARY = [&](int s) {
        if (cur >= 0) {
            __builtin_nontemporal_store(acc, &out[(long)cur * D_EMBED + lane]);
            nxt = cur + 1;
        }
        for (int z = nxt; z < s; ++z)            // empty segments -> zeros
            __builtin_nontemporal_store(0.0f, &out[(long)z * D_EMBED + lane]);
        cur = s; nxt = s; acc = 0.0f;
    };

    f32x4 r0, r1, r2, r3;       // staging regs for the NEXT batch
    int   mNext = 0, mCur = 0;

    auto REGLOAD = [&](long fb) {                // 4 x 1KB NT loads, async
        mNext = idx[fb + (lane & (BATCH - 1))];
        const f32x4* bp = (const f32x4*)(emb + fb * D_EMBED) + lane;
        r0 = __builtin_nontemporal_load(bp);
        r1 = __builtin_nontemporal_load(bp + 64);
        r2 = __builtin_nontemporal_load(bp + 128);
        r3 = __builtin_nontemporal_load(bp + 192);
    };
    auto DSWRITE = [&]() {                       // linear copy regs -> slot
        f32x4* lp = (f32x4*)lw + lane;
        lp[0]   = r0;
        lp[64]  = r1;
        lp[128] = r2;
        lp[192] = r3;
    };
    auto WALK = [&](int mseg) {                  // identical to R5's walk
#pragma unroll
        for (int j = 0; j < BATCH; ++j) {
            int s = __builtin_amdgcn_readlane(mseg, j);
            if (s != cur) BOUNDARY(s);           // wave-uniform, ~1-in-4
            acc += lw[j * D_EMBED + lane];       // ds_read_b32, 2-way alias
        }
    };

    const int nfull = (f1 - f) >> 4;             // full 16-frag batches
    long fcur = f;
    if (nfull > 0) {
        REGLOAD(fcur);
        DSWRITE();
        mCur = mNext;
    }
    for (int b = 0; b < nfull; ++b) {
        const bool more = (b + 1 < nfull);
        if (more) REGLOAD(fcur + BATCH);         // prefetch during walk
        WALK(mCur);
        if (more) { DSWRITE(); mCur = mNext; }   // waits the prefetch, stages
        fcur += BATCH;
    }

    // tail: < 16 fragments, direct scalar path (as R5)
    for (long ff = (long)f + (long)nfull * BATCH; ff < f1; ++ff) {
        int   s = idx[ff];                       // uniform
        float v = emb[ff * D_EMBED + lane];
        if (s != cur) BOUNDARY(s);
        acc += v;
    }

    // final flush + trailing empty segments
    BOUNDARY(s1);
}

extern "C" void kernel_launch(void* const* d_in, const int* in_sizes, int n_in,
                              void* d_out, int out_size, void* d_ws, size_t ws_size,
                              hipStream_t stream) {
    const float* emb = (const float*)d_in[0];
    const int*   idx = (const int*)d_in[1];
    float*       out = (float*)d_out;

    const int n_frag = in_sizes[0] / D_EMBED;   // 4,000,000
    const int n_seg  = out_size / D_EMBED;      // 1,000,000

    const int n_waves  = (n_seg + SEGS_PER_WAVE - 1) / SEGS_PER_WAVE;
    const int block    = 256;                   // 4 waves / block
    const int waves_pb = block / 64;
    const int grid     = (n_waves + waves_pb - 1) / waves_pb;

    seg_sum_kernel<<<grid, block, 0, stream>>>(emb, idx, out, n_frag, n_seg);
}

// Round 8
// 232.522 us; speedup vs baseline: 1.1907x; 1.0957x over previous
//
#include <hip/hip_runtime.h>
#include <hip/hip_bf16.h>

// Sorted segment-sum, segment-ownership (no atomics, no memset).
// R5 load/walk (16 NT dword loads per 16-frag batch, A/B 2-deep pipeline,
// readlane-driven boundary walk, register accumulator, lane = dim) +
// STORE PATH CHANGE: boundary flushes write to a per-wave 16KB LDS tile
// (all 64 segments of the wave's range), then one phase-separated burst of
// 16 x 1KB NT dwordx4 stores writes the contiguous output slab. This tests
// whether NT dword stores were failing to merge into full HBM lines.
// 1-wave blocks, 16KB LDS -> 10 blocks/CU.

#define SEGS_PER_WAVE 64
#define D_EMBED 64
#define BATCH 16

typedef float f32x4 __attribute__((ext_vector_type(4)));

__device__ inline int lower_bound(const int* __restrict__ idx, int n, int v) {
    int lo = 0, hi = n;
    while (lo < hi) {
        int mid = (lo + hi) >> 1;
        if (idx[mid] < v) lo = mid + 1; else hi = mid;
    }
    return lo;
}

__global__ __launch_bounds__(64) void seg_sum_kernel(
        const float* __restrict__ emb,
        const int*   __restrict__ idx,
        float*       __restrict__ out,
        int n_frag, int n_seg) {
    __shared__ float tile[SEGS_PER_WAVE * D_EMBED];   // 16 KB, one wave/block

    const int wave = blockIdx.x;
    const int lane = threadIdx.x;                     // 0..63, = dim

    const int s0 = wave * SEGS_PER_WAVE;
    if (s0 >= n_seg) return;
    const int s1 = min(s0 + SEGS_PER_WAVE, n_seg);

    int       f  = lower_bound(idx, n_frag, s0);
    const int f1 = lower_bound(idx, n_frag, s1);

    int   cur = -1;    // segment currently accumulating (-1 = none yet)
    int   nxt = s0;    // next segment id still needing its tile row written
    float acc = 0.0f;

    auto BOUNDARY = [&](int s) {
        if (cur >= 0) { tile[(cur - s0) * D_EMBED + lane] = acc; nxt = cur + 1; }
        for (int z = nxt; z < s; ++z)                 // empty segments -> zeros
            tile[(z - s0) * D_EMBED + lane] = 0.0f;
        cur = s; nxt = s; acc = 0.0f;
    };

    float vA[BATCH], vB[BATCH];
    int   mA = 0, mB = 0;

    auto LOAD_A = [&](long fb) {
        mA = idx[fb + (lane & (BATCH - 1))];          // one 64B line, broadcast
        const float* base = emb + fb * D_EMBED + lane;
#pragma unroll
        for (int j = 0; j < BATCH; ++j)
            vA[j] = __builtin_nontemporal_load(base + j * D_EMBED);
    };
    auto LOAD_B = [&](long fb) {
        mB = idx[fb + (lane & (BATCH - 1))];
        const float* base = emb + fb * D_EMBED + lane;
#pragma unroll
        for (int j = 0; j < BATCH; ++j)
            vB[j] = __builtin_nontemporal_load(base + j * D_EMBED);
    };
    auto WALK = [&](const float* v, int mseg) {
#pragma unroll
        for (int j = 0; j < BATCH; ++j) {
            int s = __builtin_amdgcn_readlane(mseg, j);
            if (s != cur) BOUNDARY(s);                // wave-uniform, ~1-in-4
            acc += v[j];
        }
    };

    const int nfull = (f1 - f) >> 4;                  // full 16-frag batches
    long fcur = f;
    int  b = 0;
    if (nfull > 0) LOAD_A(fcur);
    while (b < nfull) {
        if (b + 1 < nfull) LOAD_B(fcur + BATCH);      // prefetch before walk
        WALK(vA, mA);
        fcur += BATCH; ++b;
        if (b >= nfull) break;
        if (b + 1 < nfull) LOAD_A(fcur + BATCH);
        WALK(vB, mB);
        fcur += BATCH; ++b;
    }

    // tail: < 16 fragments
    for (long ff = (long)f + (long)nfull * BATCH; ff < f1; ++ff) {
        int   s = idx[ff];                            // uniform
        float v = emb[ff * D_EMBED + lane];
        if (s != cur) BOUNDARY(s);
        acc += v;
    }

    // final flush + trailing empty rows
    BOUNDARY(s1);

    // ---- phase-separated burst write: contiguous slab, 1KB per instr ----
    const int nvec = (s1 - s0) * D_EMBED / 4;         // f32x4 count (1024 full)
    const f32x4* tp = (const f32x4*)tile;
    f32x4*       op = (f32x4*)(out + (long)s0 * D_EMBED);
#pragma unroll 4
    for (int i = lane; i < nvec; i += 64)             // 16 iters: 64 lanes x 16B
        __builtin_nontemporal_store(tp[i], op + i);
}

extern "C" void kernel_launch(void* const* d_in, const int* in_sizes, int n_in,
                              void* d_out, int out_size, void* d_ws, size_t ws_size,
                              hipStream_t stream) {
    const float* emb = (const float*)d_in[0];
    const int*   idx = (const int*)d_in[1];
    float*       out = (float*)d_out;

    const int n_frag = in_sizes[0] / D_EMBED;   // 4,000,000
    const int n_seg  = out_size / D_EMBED;      // 1,000,000

    const int n_waves = (n_seg + SEGS_PER_WAVE - 1) / SEGS_PER_WAVE;  // 15625
    seg_sum_kernel<<<n_waves, 64, 0, stream>>>(emb, idx, out, n_frag, n_seg);
}